// Round 5
// baseline (213.828 us; speedup 1.0000x reference)
//
#include <hip/hip_runtime.h>

// Fused loss: 0.2 * mean(dx^2 - dy^2) + 0.8 * masked-MSE(target>0)
// dx = Sv(vert) ∘ D(horiz) on e = pred - target;  dy = D(vert) ∘ Sv(horiz)
//   Sv = [0.25, 1, 1.5, 1, 0.25], D = [-0.25, -0.5, 0, 0.5, 0.25]
// reflect-101 halo of 2 (exact; body verbatim from R10, absmax 0.0).
//
// R11 = R10 with the residency fixed. R10 post-mortem: VGPR=40 (under the
// 64-VGPR 8-waves/EU threshold) but only 1024 blocks + launch_bounds(,4)
// capped the CU at ~11 resident waves -> 2.0 TB/s, latency-bound by TLP
// starvation, 52us. Here: KR 16->8, grid (16,128)=2048 blocks, bounds
// (256,8) -> 8 blocks/CU x 4 waves = 32 waves/CU, every block resident.
// Extra halo rows (12 loads per 8-row band vs 22/16) are L2/L3-resident
// (128MB working set < 256MB Infinity Cache), so HBM fetch rises only
// mildly while TLP triples.

#define NW 4        // waves per block
#define KR 8        // output rows per wave band

__device__ __forceinline__ int reflect101(int i, int n) {
    if (i < 0) i = -i;
    if (i >= n) i = 2 * n - 2 - i;
    return i;
}

__global__ __launch_bounds__(256, 8) void loss_main(
    const float* __restrict__ pred, const float* __restrict__ target,
    double* __restrict__ part, int H, int W)
{
    __shared__ float partials[NW][3];

    const int tid  = threadIdx.x;
    const int lane = tid & 63;
    const int w    = tid >> 6;
    const int c0   = blockIdx.x * 256;
    const int band = blockIdx.y * NW + w;
    const int r0   = band * KR;

    // per-lane column offsets (loop-invariant)
    const int cc = c0 + lane * 4;                        // center float4 col
    const int cl = (cc - 2 < 0) ? 0 : (cc - 2);          // left float2 (clamped)
    const int cr = (cc + 4 > W - 2) ? (W - 2) : (cc + 4);// right float2 (clamped)
    const bool patL = (cc == 0);           // lane0 of block0: lz := e.z
    const bool patR = (cc + 4 > W - 2);    // lane63 of last block: ry := e.y

    float mse = 0.f, g = 0.f;
    unsigned cntU = 0;

    float4 D0, D1, D2, D3, D4, S0, S1, S2, S3, S4;

    auto dorow = [&](int ir, bool doMse, float4& D_, float4& S_) {
        const size_t rb = (size_t)reflect101(ir, H) * W;
        const float4 pc = *(const float4*)(pred   + rb + cc);
        const float2 pl = *(const float2*)(pred   + rb + cl);
        const float2 pr = *(const float2*)(pred   + rb + cr);
        const float4 tc = *(const float4*)(target + rb + cc);
        const float2 tl = *(const float2*)(target + rb + cl);
        const float2 tr = *(const float2*)(target + rb + cr);
        float4 e;
        e.x = pc.x - tc.x; e.y = pc.y - tc.y;
        e.z = pc.z - tc.z; e.w = pc.w - tc.w;
        float lz = pl.x - tl.x;          // e(c-2)
        float lw = pl.y - tl.y;          // e(c-1)
        float rx = pr.x - tr.x;          // e(c+4)
        float ry = pr.y - tr.y;          // e(c+5)
        // image-edge reflect patches (clamped loads give e0,e1 / e(W-2),e(W-1)):
        // reflect(-2)=2 -> e.z ; lw already e(1). reflect(W+1)=W-3 -> e.y ;
        // rx already e(W-2).
        lz = patL ? e.z : lz;
        ry = patR ? e.y : ry;
        if (doMse) {
            cntU += __popcll(__ballot(tc.x > 0.f)) + __popcll(__ballot(tc.y > 0.f))
                  + __popcll(__ballot(tc.z > 0.f)) + __popcll(__ballot(tc.w > 0.f));
            mse = fmaf(tc.x > 0.f ? e.x : 0.f, e.x, mse);
            mse = fmaf(tc.y > 0.f ? e.y : 0.f, e.y, mse);
            mse = fmaf(tc.z > 0.f ? e.z : 0.f, e.z, mse);
            mse = fmaf(tc.w > 0.f ? e.w : 0.f, e.w, mse);
        }
        D_.x = 0.25f * (e.z - lz) + 0.5f * (e.y - lw);
        D_.y = 0.25f * (e.w - lw) + 0.5f * (e.z - e.x);
        D_.z = 0.25f * (rx  - e.x) + 0.5f * (e.w - e.y);
        D_.w = 0.25f * (ry  - e.y) + 0.5f * (rx  - e.z);
        S_.x = 0.25f * (lz + e.z) + (lw  + e.y) + 1.5f * e.x;
        S_.y = 0.25f * (lw + e.w) + (e.x + e.z) + 1.5f * e.y;
        S_.z = 0.25f * (e.x + rx) + (e.y + e.w) + 1.5f * e.z;
        S_.w = 0.25f * (e.y + ry) + (e.z + rx ) + 1.5f * e.w;
    };

    auto emit = [&]() {
        const float dx0 = 0.25f * (D0.x + D4.x) + (D1.x + D3.x) + 1.5f * D2.x;
        const float dx1 = 0.25f * (D0.y + D4.y) + (D1.y + D3.y) + 1.5f * D2.y;
        const float dx2 = 0.25f * (D0.z + D4.z) + (D1.z + D3.z) + 1.5f * D2.z;
        const float dx3 = 0.25f * (D0.w + D4.w) + (D1.w + D3.w) + 1.5f * D2.w;
        const float dy0 = 0.25f * (S4.x - S0.x) + 0.5f * (S3.x - S1.x);
        const float dy1 = 0.25f * (S4.y - S0.y) + 0.5f * (S3.y - S1.y);
        const float dy2 = 0.25f * (S4.z - S0.z) + 0.5f * (S3.z - S1.z);
        const float dy3 = 0.25f * (S4.w - S0.w) + 0.5f * (S3.w - S1.w);
        g += (dx0 * dx0 - dy0 * dy0) + (dx1 * dx1 - dy1 * dy1)
           + (dx2 * dx2 - dy2 * dy2) + (dx3 * dx3 - dy3 * dy3);
    };
    auto shift = [&]() {
        D0 = D1; D1 = D2; D2 = D3; D3 = D4;
        S0 = S1; S1 = S2; S2 = S3; S3 = S4;
    };

    // prologue: rows r0-2 .. r0+1. MSE exactly on rows r0, r0+1 (for band 0
    // the reflected dup rows 2,1 carry doMse=false -> each row counted once).
    dorow(r0 - 2, false, D0, S0);
    dorow(r0 - 1, false, D1, S1);
    dorow(r0 + 0, true,  D2, S2);
    dorow(r0 + 1, true,  D3, S3);

    // hot loop: rows r0+2 .. r0+KR-1, all with MSE, zero runtime predicates
#pragma unroll 2
    for (int k = 0; k < KR - 2; ++k) {
        dorow(r0 + 2 + k, true, D4, S4);
        emit();
        shift();
    }
    // tail: rows r0+KR, r0+KR+1 (next band's MSE rows / reflected) -> no MSE
    dorow(r0 + KR,     false, D4, S4); emit(); shift();
    dorow(r0 + KR + 1, false, D4, S4); emit();

    // ---- reduction: wave shuffle -> LDS partials -> private ws slot ----
    for (int off = 32; off > 0; off >>= 1) {
        mse += __shfl_down(mse, off, 64);
        g   += __shfl_down(g,   off, 64);
    }
    if (lane == 0) {
        partials[w][0] = mse;
        partials[w][1] = (float)cntU;   // ballot count: wave-uniform
        partials[w][2] = g;
    }
    __syncthreads();
    if (tid == 0) {
        float m = 0.f, c2 = 0.f, gg = 0.f;
        for (int wv = 0; wv < NW; ++wv) {
            m  += partials[wv][0];
            c2 += partials[wv][1];
            gg += partials[wv][2];
        }
        const int bid = blockIdx.y * gridDim.x + blockIdx.x;
        double* slot = part + 3 * bid;
        slot[0] = (double)m;
        slot[1] = (double)c2;
        slot[2] = (double)gg;
    }
}

__global__ __launch_bounds__(256) void loss_final(
    const double* __restrict__ part, int nslots,
    float* __restrict__ out, double inv_hw)
{
    __shared__ double red[4][3];
    double m = 0.0, c = 0.0, g = 0.0;
    for (int s = threadIdx.x; s < nslots; s += 256) {
        m += part[3 * s];
        c += part[3 * s + 1];
        g += part[3 * s + 2];
    }
    for (int off = 32; off > 0; off >>= 1) {
        m += __shfl_down(m, off, 64);
        c += __shfl_down(c, off, 64);
        g += __shfl_down(g, off, 64);
    }
    const int w = threadIdx.x >> 6;
    if ((threadIdx.x & 63) == 0) { red[w][0] = m; red[w][1] = c; red[w][2] = g; }
    __syncthreads();
    if (threadIdx.x == 0) {
        m = red[0][0] + red[1][0] + red[2][0] + red[3][0];
        c = red[0][1] + red[1][1] + red[2][1] + red[3][1];
        g = red[0][2] + red[1][2] + red[2][2] + red[3][2];
        const double cnt = c < 1.0 ? 1.0 : c;
        out[0] = (float)(0.2 * (g * inv_hw) + 0.8 * (m / cnt));
    }
}

extern "C" void kernel_launch(void* const* d_in, const int* in_sizes, int n_in,
                              void* d_out, int out_size, void* d_ws, size_t ws_size,
                              hipStream_t stream) {
    const float* pred   = (const float*)d_in[0];
    const float* target = (const float*)d_in[1];
    float* out   = (float*)d_out;
    double* part = (double*)d_ws;

    const int H = 4096, W = 4096;
    dim3 grid(W / 256, H / (NW * KR));    // (16, 128) = 2048 blocks, 8/CU resident
    const int nblocks = grid.x * grid.y;  // 2048 slots = 48 KB of ws

    loss_main<<<grid, 256, 0, stream>>>(pred, target, part, H, W);
    loss_final<<<1, 256, 0, stream>>>(part, nblocks, out,
                                      1.0 / ((double)H * (double)W));
}

// Round 6
// 155.547 us; speedup vs baseline: 1.3747x; 1.3747x over previous
//
#include <hip/hip_runtime.h>

// Fused loss: 0.2 * mean(dx^2 - dy^2) + 0.8 * masked-MSE(target>0)
// dx = Sv(vert) ∘ D(horiz) on e = pred - target;  dy = D(vert) ∘ Sv(horiz)
//   Sv = [0.25, 1, 1.5, 1, 0.25], D = [-0.25, -0.5, 0, 0.5, 0.25]
// reflect-101 halo of 2 (exact; body verbatim from R10, absmax 0.0).
//
// R12 = R11 with the launch_bounds revert. R11 post-mortem: bounds(256,8)
// forced VGPR 40->32 and spilled the rolling window (WRITE_SIZE 113MB
// sentinel) -- yet occupancy 71% and BW 2.75 TB/s even while spilling,
// confirming the TLP theory. launch_bounds' 2nd arg is a compiler floor,
// not a HW cap: at R10's natural 40 VGPR (<=64) the HW residents 8
// waves/EU by itself. So: keep KR=8 + 2048 blocks (8 blocks/CU resident),
// restore bounds(256,4) -> identical codegen to R10 (40 VGPR, no spill).

#define NW 4        // waves per block
#define KR 8        // output rows per wave band

__device__ __forceinline__ int reflect101(int i, int n) {
    if (i < 0) i = -i;
    if (i >= n) i = 2 * n - 2 - i;
    return i;
}

__global__ __launch_bounds__(256, 4) void loss_main(
    const float* __restrict__ pred, const float* __restrict__ target,
    double* __restrict__ part, int H, int W)
{
    __shared__ float partials[NW][3];

    const int tid  = threadIdx.x;
    const int lane = tid & 63;
    const int w    = tid >> 6;
    const int c0   = blockIdx.x * 256;
    const int band = blockIdx.y * NW + w;
    const int r0   = band * KR;

    // per-lane column offsets (loop-invariant)
    const int cc = c0 + lane * 4;                        // center float4 col
    const int cl = (cc - 2 < 0) ? 0 : (cc - 2);          // left float2 (clamped)
    const int cr = (cc + 4 > W - 2) ? (W - 2) : (cc + 4);// right float2 (clamped)
    const bool patL = (cc == 0);           // lane0 of block0: lz := e.z
    const bool patR = (cc + 4 > W - 2);    // lane63 of last block: ry := e.y

    float mse = 0.f, g = 0.f;
    unsigned cntU = 0;

    float4 D0, D1, D2, D3, D4, S0, S1, S2, S3, S4;

    auto dorow = [&](int ir, bool doMse, float4& D_, float4& S_) {
        const size_t rb = (size_t)reflect101(ir, H) * W;
        const float4 pc = *(const float4*)(pred   + rb + cc);
        const float2 pl = *(const float2*)(pred   + rb + cl);
        const float2 pr = *(const float2*)(pred   + rb + cr);
        const float4 tc = *(const float4*)(target + rb + cc);
        const float2 tl = *(const float2*)(target + rb + cl);
        const float2 tr = *(const float2*)(target + rb + cr);
        float4 e;
        e.x = pc.x - tc.x; e.y = pc.y - tc.y;
        e.z = pc.z - tc.z; e.w = pc.w - tc.w;
        float lz = pl.x - tl.x;          // e(c-2)
        float lw = pl.y - tl.y;          // e(c-1)
        float rx = pr.x - tr.x;          // e(c+4)
        float ry = pr.y - tr.y;          // e(c+5)
        // image-edge reflect patches (clamped loads give e0,e1 / e(W-2),e(W-1)):
        // reflect(-2)=2 -> e.z ; lw already e(1). reflect(W+1)=W-3 -> e.y ;
        // rx already e(W-2).
        lz = patL ? e.z : lz;
        ry = patR ? e.y : ry;
        if (doMse) {
            cntU += __popcll(__ballot(tc.x > 0.f)) + __popcll(__ballot(tc.y > 0.f))
                  + __popcll(__ballot(tc.z > 0.f)) + __popcll(__ballot(tc.w > 0.f));
            mse = fmaf(tc.x > 0.f ? e.x : 0.f, e.x, mse);
            mse = fmaf(tc.y > 0.f ? e.y : 0.f, e.y, mse);
            mse = fmaf(tc.z > 0.f ? e.z : 0.f, e.z, mse);
            mse = fmaf(tc.w > 0.f ? e.w : 0.f, e.w, mse);
        }
        D_.x = 0.25f * (e.z - lz) + 0.5f * (e.y - lw);
        D_.y = 0.25f * (e.w - lw) + 0.5f * (e.z - e.x);
        D_.z = 0.25f * (rx  - e.x) + 0.5f * (e.w - e.y);
        D_.w = 0.25f * (ry  - e.y) + 0.5f * (rx  - e.z);
        S_.x = 0.25f * (lz + e.z) + (lw  + e.y) + 1.5f * e.x;
        S_.y = 0.25f * (lw + e.w) + (e.x + e.z) + 1.5f * e.y;
        S_.z = 0.25f * (e.x + rx) + (e.y + e.w) + 1.5f * e.z;
        S_.w = 0.25f * (e.y + ry) + (e.z + rx ) + 1.5f * e.w;
    };

    auto emit = [&]() {
        const float dx0 = 0.25f * (D0.x + D4.x) + (D1.x + D3.x) + 1.5f * D2.x;
        const float dx1 = 0.25f * (D0.y + D4.y) + (D1.y + D3.y) + 1.5f * D2.y;
        const float dx2 = 0.25f * (D0.z + D4.z) + (D1.z + D3.z) + 1.5f * D2.z;
        const float dx3 = 0.25f * (D0.w + D4.w) + (D1.w + D3.w) + 1.5f * D2.w;
        const float dy0 = 0.25f * (S4.x - S0.x) + 0.5f * (S3.x - S1.x);
        const float dy1 = 0.25f * (S4.y - S0.y) + 0.5f * (S3.y - S1.y);
        const float dy2 = 0.25f * (S4.z - S0.z) + 0.5f * (S3.z - S1.z);
        const float dy3 = 0.25f * (S4.w - S0.w) + 0.5f * (S3.w - S1.w);
        g += (dx0 * dx0 - dy0 * dy0) + (dx1 * dx1 - dy1 * dy1)
           + (dx2 * dx2 - dy2 * dy2) + (dx3 * dx3 - dy3 * dy3);
    };
    auto shift = [&]() {
        D0 = D1; D1 = D2; D2 = D3; D3 = D4;
        S0 = S1; S1 = S2; S2 = S3; S3 = S4;
    };

    // prologue: rows r0-2 .. r0+1. MSE exactly on rows r0, r0+1 (for band 0
    // the reflected dup rows 2,1 carry doMse=false -> each row counted once).
    dorow(r0 - 2, false, D0, S0);
    dorow(r0 - 1, false, D1, S1);
    dorow(r0 + 0, true,  D2, S2);
    dorow(r0 + 1, true,  D3, S3);

    // hot loop: rows r0+2 .. r0+KR-1, all with MSE, zero runtime predicates
#pragma unroll 2
    for (int k = 0; k < KR - 2; ++k) {
        dorow(r0 + 2 + k, true, D4, S4);
        emit();
        shift();
    }
    // tail: rows r0+KR, r0+KR+1 (next band's MSE rows / reflected) -> no MSE
    dorow(r0 + KR,     false, D4, S4); emit(); shift();
    dorow(r0 + KR + 1, false, D4, S4); emit();

    // ---- reduction: wave shuffle -> LDS partials -> private ws slot ----
    for (int off = 32; off > 0; off >>= 1) {
        mse += __shfl_down(mse, off, 64);
        g   += __shfl_down(g,   off, 64);
    }
    if (lane == 0) {
        partials[w][0] = mse;
        partials[w][1] = (float)cntU;   // ballot count: wave-uniform
        partials[w][2] = g;
    }
    __syncthreads();
    if (tid == 0) {
        float m = 0.f, c2 = 0.f, gg = 0.f;
        for (int wv = 0; wv < NW; ++wv) {
            m  += partials[wv][0];
            c2 += partials[wv][1];
            gg += partials[wv][2];
        }
        const int bid = blockIdx.y * gridDim.x + blockIdx.x;
        double* slot = part + 3 * bid;
        slot[0] = (double)m;
        slot[1] = (double)c2;
        slot[2] = (double)gg;
    }
}

__global__ __launch_bounds__(256) void loss_final(
    const double* __restrict__ part, int nslots,
    float* __restrict__ out, double inv_hw)
{
    __shared__ double red[4][3];
    double m = 0.0, c = 0.0, g = 0.0;
    for (int s = threadIdx.x; s < nslots; s += 256) {
        m += part[3 * s];
        c += part[3 * s + 1];
        g += part[3 * s + 2];
    }
    for (int off = 32; off > 0; off >>= 1) {
        m += __shfl_down(m, off, 64);
        c += __shfl_down(c, off, 64);
        g += __shfl_down(g, off, 64);
    }
    const int w = threadIdx.x >> 6;
    if ((threadIdx.x & 63) == 0) { red[w][0] = m; red[w][1] = c; red[w][2] = g; }
    __syncthreads();
    if (threadIdx.x == 0) {
        m = red[0][0] + red[1][0] + red[2][0] + red[3][0];
        c = red[0][1] + red[1][1] + red[2][1] + red[3][1];
        g = red[0][2] + red[1][2] + red[2][2] + red[3][2];
        const double cnt = c < 1.0 ? 1.0 : c;
        out[0] = (float)(0.2 * (g * inv_hw) + 0.8 * (m / cnt));
    }
}

extern "C" void kernel_launch(void* const* d_in, const int* in_sizes, int n_in,
                              void* d_out, int out_size, void* d_ws, size_t ws_size,
                              hipStream_t stream) {
    const float* pred   = (const float*)d_in[0];
    const float* target = (const float*)d_in[1];
    float* out   = (float*)d_out;
    double* part = (double*)d_ws;

    const int H = 4096, W = 4096;
    dim3 grid(W / 256, H / (NW * KR));    // (16, 128) = 2048 blocks, 8/CU resident
    const int nblocks = grid.x * grid.y;  // 2048 slots = 48 KB of ws

    loss_main<<<grid, 256, 0, stream>>>(pred, target, part, H, W);
    loss_final<<<1, 256, 0, stream>>>(part, nblocks, out,
                                      1.0 / ((double)H * (double)W));
}